// Round 2
// baseline (105.000 us; speedup 1.0000x reference)
//
#include <hip/hip_runtime.h>
#include <math.h>

// RBF pairwise kernel: out[i,j] = var * exp(-0.5 * sum_d ((x[i,d]-xx[j,d])/s[d])^2)
// N=M=4096, D=16, fp32 in/out.
//
// R5: occupancy-doubled variant. Theory: R3/R4 (~43 us kernel vs ~6 us issue
// arithmetic) are latency-stall-bound at 4 waves/SIMD (launch_bounds(256,4),
// ~100 VGPR). Halve per-lane state -> <=64 VGPR -> 8 waves/SIMD (32 waves/CU,
// 100% occupancy) for 2x the latency hiding on the load->fma-chain->exp->store
// dependency path.
//
//   out[i,j] = exp2( x_i . b_j - cc_i - dn_j ),
//     b_j  = xx_j * inv^2 * log2(e)          (per-lane regs, 2 rows = 32 VGPR)
//     cc_i = log2(e)*(0.5|x_i/s|^2 - lnvar)  (LDS, 1 b32 broadcast per row)
//     dn_j = log2(e)*0.5|xx_j/s|^2           (per-lane regs)
//
// Tile 16 rows x 512 cols, grid (8,256)=2048 blocks = 8 blocks/CU:
//   - lane l of wave w owns j = j0 + 128w + 2l -> float2 stores; the 4 waves
//     are adjacent in j -> 2 KB contiguous per row per block.
//   - a-row read raw from x at a block-uniform address (uniformity analysis
//     -> s_load; worst case a single broadcast cacheline) -> no LDS b128 and
//     no VGPR cost for the A operand in the hot loop.

#define NN 4096
#define MM 4096
#define DD 16
#define L2E 1.44269504f     // log2(e)
#define HL2E 0.72134752f    // 0.5*log2(e)

__global__ __launch_bounds__(256, 8)
void rbf_kernel(const float* __restrict__ x, const float* __restrict__ xx,
                const float* __restrict__ scale_ff,
                const float* __restrict__ variance_ff,
                float* __restrict__ out) {
  __shared__ __align__(16) float s_inv[DD];  // 1/softplus(scale_ff)
  __shared__ __align__(16) float s_il[DD];   // inv * log2(e)
  __shared__ float s_lnvarL;                 // log2(e) * ln(softplus(var_ff))
  __shared__ float s_cc[16];                 // per-row constant

  const int tid  = threadIdx.x;
  const int lane = tid & 63;
  const int wave = tid >> 6;

  const int i0 = blockIdx.y * 16;   // 16 output rows per block
  const int j0 = blockIdx.x * 512;  // 512 output cols per block

  // phase 1: scales
  if (tid < DD) {
    const float sp  = log1pf(expf(scale_ff[tid]));
    const float inv = 1.0f / sp;
    s_inv[tid] = inv;
    s_il[tid]  = inv * L2E;
  }
  if (tid == DD) {
    s_lnvarL = L2E * logf(log1pf(expf(variance_ff[0])));
  }
  __syncthreads();

  // phase 2a: cc_i for the block's 16 x-rows (16 threads)
  if (tid < 16) {
    float s = 0.f;
    const float* xp = x + (size_t)(i0 + tid) * DD;
#pragma unroll
    for (int c = 0; c < 4; ++c) {
      const float4 v  = *(const float4*)(xp + 4 * c);
      const float4 iv = *(const float4*)&s_inv[4 * c];
      const float ax = v.x * iv.x, ay = v.y * iv.y;
      const float az = v.z * iv.z, aw = v.w * iv.w;
      s = fmaf(ax, ax, s); s = fmaf(ay, ay, s);
      s = fmaf(az, az, s); s = fmaf(aw, aw, s);
    }
    s_cc[tid] = fmaf(HL2E, s, -s_lnvarL);   // L*(0.5|a|^2 - lnvar)
  }

  // phase 2b: per-lane xx fragment: 2 rows j = j0 + 128*wave + 2*lane, +1.
  // iv/il re-read from LDS per column to keep prologue register peak low.
  float4 b[2][4];
  float ndn[2];
  const int jb = j0 + (wave << 7) + (lane << 1);
#pragma unroll
  for (int r = 0; r < 2; ++r) {
    float s = 0.f;
#pragma unroll
    for (int c = 0; c < 4; ++c) {
      const float4 v  = *(const float4*)&xx[(size_t)(jb + r) * DD + 4 * c];
      const float4 iv = *(const float4*)&s_inv[4 * c];
      const float4 il = *(const float4*)&s_il[4 * c];
      const float tx = v.x * iv.x, ty = v.y * iv.y;
      const float tz = v.z * iv.z, tw = v.w * iv.w;
      s = fmaf(tx, tx, s); s = fmaf(ty, ty, s);
      s = fmaf(tz, tz, s); s = fmaf(tw, tw, s);
      b[r][c].x = tx * il.x; b[r][c].y = ty * il.y;
      b[r][c].z = tz * il.z; b[r][c].w = tw * il.w;
    }
    ndn[r] = -HL2E * s;                     // -L*0.5|b|^2
  }

  __syncthreads();  // s_cc ready

  const float* __restrict__ xw = x + (size_t)i0 * DD;   // block-uniform
  float* __restrict__ op = out + (size_t)i0 * MM + jb;

#pragma unroll
  for (int ii = 0; ii < 16; ++ii) {
    const float4 a0 = *(const float4*)(xw + ii * DD + 0);
    const float4 a1 = *(const float4*)(xw + ii * DD + 4);
    const float4 a2 = *(const float4*)(xw + ii * DD + 8);
    const float4 a3 = *(const float4*)(xw + ii * DD + 12);
    const float cc  = s_cc[ii];             // 1 ds_read_b32 broadcast

    float acc0 = ndn[0] - cc;
    float acc1 = ndn[1] - cc;

    acc0 = fmaf(a0.x, b[0][0].x, acc0); acc0 = fmaf(a0.y, b[0][0].y, acc0);
    acc0 = fmaf(a0.z, b[0][0].z, acc0); acc0 = fmaf(a0.w, b[0][0].w, acc0);
    acc0 = fmaf(a1.x, b[0][1].x, acc0); acc0 = fmaf(a1.y, b[0][1].y, acc0);
    acc0 = fmaf(a1.z, b[0][1].z, acc0); acc0 = fmaf(a1.w, b[0][1].w, acc0);
    acc0 = fmaf(a2.x, b[0][2].x, acc0); acc0 = fmaf(a2.y, b[0][2].y, acc0);
    acc0 = fmaf(a2.z, b[0][2].z, acc0); acc0 = fmaf(a2.w, b[0][2].w, acc0);
    acc0 = fmaf(a3.x, b[0][3].x, acc0); acc0 = fmaf(a3.y, b[0][3].y, acc0);
    acc0 = fmaf(a3.z, b[0][3].z, acc0); acc0 = fmaf(a3.w, b[0][3].w, acc0);

    acc1 = fmaf(a0.x, b[1][0].x, acc1); acc1 = fmaf(a0.y, b[1][0].y, acc1);
    acc1 = fmaf(a0.z, b[1][0].z, acc1); acc1 = fmaf(a0.w, b[1][0].w, acc1);
    acc1 = fmaf(a1.x, b[1][1].x, acc1); acc1 = fmaf(a1.y, b[1][1].y, acc1);
    acc1 = fmaf(a1.z, b[1][1].z, acc1); acc1 = fmaf(a1.w, b[1][1].w, acc1);
    acc1 = fmaf(a2.x, b[1][2].x, acc1); acc1 = fmaf(a2.y, b[1][2].y, acc1);
    acc1 = fmaf(a2.z, b[1][2].z, acc1); acc1 = fmaf(a2.w, b[1][2].w, acc1);
    acc1 = fmaf(a3.x, b[1][3].x, acc1); acc1 = fmaf(a3.y, b[1][3].y, acc1);
    acc1 = fmaf(a3.z, b[1][3].z, acc1); acc1 = fmaf(a3.w, b[1][3].w, acc1);

    float2 o;
    o.x = __builtin_amdgcn_exp2f(acc0);
    o.y = __builtin_amdgcn_exp2f(acc1);
    *(float2*)(op + (size_t)ii * MM) = o;   // 4 waves adjacent -> 2 KB/row burst
  }
}

extern "C" void kernel_launch(void* const* d_in, const int* in_sizes, int n_in,
                              void* d_out, int out_size, void* d_ws, size_t ws_size,
                              hipStream_t stream) {
  const float* x   = (const float*)d_in[0];   // [4096,16]
  const float* xx  = (const float*)d_in[1];   // [4096,16]
  const float* sc  = (const float*)d_in[2];   // [16]
  const float* var = (const float*)d_in[3];   // [1]
  float* out = (float*)d_out;                 // [4096,4096]

  dim3 grid(MM / 512, NN / 16);               // (8, 256) = 2048 blocks = 8/CU
  dim3 block(256);
  rbf_kernel<<<grid, block, 0, stream>>>(x, xx, sc, var, out);
}

// Round 4
// 91.643 us; speedup vs baseline: 1.1457x; 1.1457x over previous
//
#include <hip/hip_runtime.h>
#include <math.h>

// RBF pairwise kernel: out[i,j] = var * exp(-0.5 * sum_d ((x[i,d]-xx[j,d])/s[d])^2)
// N=M=4096, D=16, fp32 in/out.
//
// R6b = R3 (verified best, 89.1 us) + three strictly-local changes:
//   1. NONTEMPORAL float4 stores (via clang ext_vector_type -- the HIP
//      float4 class type is rejected by __builtin_nontemporal_store).
//      Output (64 MiB) is write-once/never-read; nt bypasses L2/L3
//      write-allocate. The harness poison-fill leaves 256 MiB of dirty
//      lines in cache; allocating stores pay evictions.
//   2. log2(e) pre-folded into b and cc -> native v_exp_f32 (exp2), saving
//      4 v_mul per ii per lane vs __expf.
//   3. acc starts at ndn[r]-cc, saving 8 v_sub per ii per lane.
// Everything else (tile 64x256, launch_bounds(256,4), LDS a-tile broadcast
// reads, float4 j-in-lane stores, grid (16,64)) is byte-identical to R3 --
// R4 (16x1024 remap) and R5 (occupancy 8) both REGRESSED; do not revisit.

#define NN 4096
#define MM 4096
#define DD 16
#define RS 20   // LDS row stride: 16 data + 1 c + 3 pad (80 B, 16-aligned)
#define L2E 1.44269504f     // log2(e)
#define HL2E 0.72134752f    // 0.5*log2(e)

typedef float f32x4 __attribute__((ext_vector_type(4)));

__global__ __launch_bounds__(256, 4)
void rbf_kernel(const float* __restrict__ x, const float* __restrict__ xx,
                const float* __restrict__ scale_ff,
                const float* __restrict__ variance_ff,
                float* __restrict__ out) {
  __shared__ __align__(16) float s_inv[DD];     // 1/softplus(scale_ff)
  __shared__ float s_lnvarL;                    // log2(e)*ln(softplus(var))
  __shared__ __align__(16) float s_a[64 * RS];  // a rows + cc_i

  const int tid  = threadIdx.x;
  const int lane = tid & 63;
  const int wave = tid >> 6;

  const int i0 = blockIdx.y * 64;
  const int j0 = blockIdx.x * 256;

  if (tid < DD) {
    s_inv[tid] = 1.0f / log1pf(expf(scale_ff[tid]));
  }
  if (tid == DD) {
    s_lnvarL = L2E * logf(log1pf(expf(variance_ff[0])));
  }
  __syncthreads();

  // Stage a = x/s tile (64 rows) into LDS. 256 threads x 1 float4.
  {
    const int row = tid >> 2;
    const int c   = tid & 3;
    float4 xv = *(const float4*)&x[(i0 + row) * DD + c * 4];
    float4 iv = *(const float4*)&s_inv[c * 4];
    xv.x *= iv.x; xv.y *= iv.y; xv.z *= iv.z; xv.w *= iv.w;
    *(float4*)&s_a[row * RS + c * 4] = xv;
  }
  __syncthreads();

  // cc_i = L*(0.5*|a_i|^2) - L*lnvar, one thread per row (once per block).
  if (tid < 64) {
    float s = 0.f;
#pragma unroll
    for (int c = 0; c < 4; ++c) {
      float4 v = *(const float4*)&s_a[tid * RS + c * 4];
      s = fmaf(v.x, v.x, s); s = fmaf(v.y, v.y, s);
      s = fmaf(v.z, v.z, s); s = fmaf(v.w, v.w, s);
    }
    s_a[tid * RS + DD] = fmaf(HL2E, s, -s_lnvarL);
  }

  // Per-lane xx fragment: 4 rows (j0+4*lane..+3), bL = (xx/s)*L2E, + dnL.
  float4 b[4][4];
  float ndn[4];
  {
    float4 iv[4];
#pragma unroll
    for (int c = 0; c < 4; ++c) iv[c] = *(const float4*)&s_inv[c * 4];
    const int jb = j0 + (lane << 2);
#pragma unroll
    for (int r = 0; r < 4; ++r) {
      float s = 0.f;
#pragma unroll
      for (int c = 0; c < 4; ++c) {
        float4 v = *(const float4*)&xx[(size_t)(jb + r) * DD + c * 4];
        const float tx = v.x * iv[c].x, ty = v.y * iv[c].y;
        const float tz = v.z * iv[c].z, tw = v.w * iv[c].w;
        s = fmaf(tx, tx, s); s = fmaf(ty, ty, s);
        s = fmaf(tz, tz, s); s = fmaf(tw, tw, s);
        b[r][c].x = tx * L2E; b[r][c].y = ty * L2E;
        b[r][c].z = tz * L2E; b[r][c].w = tw * L2E;
      }
      ndn[r] = -HL2E * s;              // -L*0.5|b_nat|^2
    }
  }

  __syncthreads();  // s_a (rows + cc) ready

  const int jb = j0 + (lane << 2);

#pragma unroll 2
  for (int ii = 0; ii < 16; ++ii) {
    const int li = wave * 16 + ii;                    // local row in tile
    const float* ap = &s_a[li * RS];                  // wave-uniform -> broadcast
    const float4 a0 = *(const float4*)&ap[0];
    const float4 a1 = *(const float4*)&ap[4];
    const float4 a2 = *(const float4*)&ap[8];
    const float4 a3 = *(const float4*)&ap[12];
    const float cc  = ap[DD];

    float acc[4];
#pragma unroll
    for (int r = 0; r < 4; ++r) acc[r] = ndn[r] - cc;

#pragma unroll
    for (int r = 0; r < 4; ++r) {
      float s = acc[r];
      s = fmaf(a0.x, b[r][0].x, s); s = fmaf(a0.y, b[r][0].y, s);
      s = fmaf(a0.z, b[r][0].z, s); s = fmaf(a0.w, b[r][0].w, s);
      s = fmaf(a1.x, b[r][1].x, s); s = fmaf(a1.y, b[r][1].y, s);
      s = fmaf(a1.z, b[r][1].z, s); s = fmaf(a1.w, b[r][1].w, s);
      s = fmaf(a2.x, b[r][2].x, s); s = fmaf(a2.y, b[r][2].y, s);
      s = fmaf(a2.z, b[r][2].z, s); s = fmaf(a2.w, b[r][2].w, s);
      s = fmaf(a3.x, b[r][3].x, s); s = fmaf(a3.y, b[r][3].y, s);
      s = fmaf(a3.z, b[r][3].z, s); s = fmaf(a3.w, b[r][3].w, s);
      acc[r] = s;
    }

    f32x4 o;
    o.x = __builtin_amdgcn_exp2f(acc[0]);
    o.y = __builtin_amdgcn_exp2f(acc[1]);
    o.z = __builtin_amdgcn_exp2f(acc[2]);
    o.w = __builtin_amdgcn_exp2f(acc[3]);
    // Nontemporal: stream past L2/L3, no write-allocate (output never re-read).
    __builtin_nontemporal_store(o, (f32x4*)&out[(size_t)(i0 + li) * MM + jb]);
  }
}

extern "C" void kernel_launch(void* const* d_in, const int* in_sizes, int n_in,
                              void* d_out, int out_size, void* d_ws, size_t ws_size,
                              hipStream_t stream) {
  const float* x   = (const float*)d_in[0];   // [4096,16]
  const float* xx  = (const float*)d_in[1];   // [4096,16]
  const float* sc  = (const float*)d_in[2];   // [16]
  const float* var = (const float*)d_in[3];   // [1]
  float* out = (float*)d_out;                 // [4096,4096]

  dim3 grid(MM / 256, NN / 64);               // (16, 64) = 1024 blocks, as R3
  dim3 block(256);
  rbf_kernel<<<grid, block, 0, stream>>>(x, xx, sc, var, out);
}